// Round 3
// baseline (1317.413 us; speedup 1.0000x reference)
//
#include <hip/hip_runtime.h>
#include <math.h>

#define HH 12
#define SS 2048
#define DM 768
#define DK 64

typedef _Float16 f16x8 __attribute__((ext_vector_type(8)));
typedef _Float16 f16x4 __attribute__((ext_vector_type(4)));
typedef float    f32x4 __attribute__((ext_vector_type(4)));

#define MFMA_F16(A, B, C) __builtin_amdgcn_mfma_f32_16x16x32_f16((A), (B), (C), 0, 0, 0)

// ---------------------------------------------------------------------------
// conv_w: W[k][n] fp32 -> transposed split-f16 planes Wt{hi,lo}[n][k].
// One 64x64 tile per block, LDS transpose. blockIdx.z selects the weight.
// ---------------------------------------------------------------------------
__global__ __launch_bounds__(256) void conv_w_kernel(
        const float* __restrict__ w0, const float* __restrict__ w1,
        const float* __restrict__ w2, const float* __restrict__ w3,
        _Float16* hi0, _Float16* lo0, _Float16* hi1, _Float16* lo1,
        _Float16* hi2, _Float16* lo2, _Float16* hi3, _Float16* lo3)
{
    __shared__ float T[64][68];
    const int z = blockIdx.z;
    const float* W = (z == 0) ? w0 : (z == 1) ? w1 : (z == 2) ? w2 : w3;
    _Float16* Whi  = (z == 0) ? hi0 : (z == 1) ? hi1 : (z == 2) ? hi2 : hi3;
    _Float16* Wlo  = (z == 0) ? lo0 : (z == 1) ? lo1 : (z == 2) ? lo2 : lo3;

    const int tid = threadIdx.x;
    const int k0 = blockIdx.y * 64, n0 = blockIdx.x * 64;

    #pragma unroll
    for (int i = 0; i < 4; ++i) {
        int r = (tid >> 4) + i * 16;
        int c = (tid & 15) * 4;
        *(float4*)&T[r][c] = *(const float4*)&W[(size_t)(k0 + r) * DM + n0 + c];
    }
    __syncthreads();

    const int n = tid >> 2, kq = (tid & 3) * 16;
    f16x8 ha, la, hb, lb;
    #pragma unroll
    for (int j = 0; j < 8; ++j) {
        float v = T[kq + j][n];
        _Float16 h = (_Float16)v;
        ha[j] = h; la[j] = (_Float16)(v - (float)h);
    }
    #pragma unroll
    for (int j = 0; j < 8; ++j) {
        float v = T[kq + 8 + j][n];
        _Float16 h = (_Float16)v;
        hb[j] = h; lb[j] = (_Float16)(v - (float)h);
    }
    size_t o = (size_t)(n0 + n) * DM + k0 + kq;
    *(f16x8*)&Whi[o]     = ha;
    *(f16x8*)&Whi[o + 8] = hb;
    *(f16x8*)&Wlo[o]     = la;
    *(f16x8*)&Wlo[o + 8] = lb;
}

// ---------------------------------------------------------------------------
// gemm16: C[4096,768] = A[4096,768] @ W[768,768] + bias, split-fp16 MFMA.
// A fp32, split hi/lo in registers per fragment. B pre-split transposed Wt[n][k].
// No LDS in the main loop; fragments direct from global (L1/L2-resident W).
// Block = 4 waves, 64x64 tile; wave w owns rows w*16..w*16+15, all 64 n.
// MODE 0: f16 hi/lo head-split [B,H,S,64]            (Q, K)
// MODE 1: f16 hi/lo head-split transposed [B,H,64,S] (V), via LDS transpose
// MODE 2: fp32 flat [M,768]                          (final out -> Cf)
// ---------------------------------------------------------------------------
template <int MODE>
__global__ __launch_bounds__(256) void gemm16_kernel(
        const float* __restrict__ A, const _Float16* __restrict__ Bhi,
        const _Float16* __restrict__ Blo, const float* __restrict__ bias,
        _Float16* __restrict__ Chi, _Float16* __restrict__ Clo,
        float* __restrict__ Cf)
{
    const int tid  = threadIdx.x;
    const int wave = tid >> 6, lane = tid & 63;
    const int lrow = lane & 15;
    const int lk   = (lane >> 4) * 8;
    const int grow = (lane >> 4) * 4;
    const int n0   = blockIdx.x * 64;
    const int m0   = blockIdx.y * 64;
    const int mr   = m0 + wave * 16 + lrow;   // this lane's A-fragment row

    f32x4 acc[4];
    #pragma unroll
    for (int nf = 0; nf < 4; ++nf) acc[nf] = (f32x4){0.f, 0.f, 0.f, 0.f};

    const float* Arow = A + (size_t)mr * DM;

    #pragma unroll 2
    for (int kt = 0; kt < 24; ++kt) {
        const int k0 = kt * 32 + lk;
        float4 x = *(const float4*)&Arow[k0];
        float4 y = *(const float4*)&Arow[k0 + 4];
        float vv[8] = {x.x, x.y, x.z, x.w, y.x, y.y, y.z, y.w};
        f16x8 ah, al;
        #pragma unroll
        for (int j = 0; j < 8; ++j) {
            _Float16 h = (_Float16)vv[j];
            ah[j] = h; al[j] = (_Float16)(vv[j] - (float)h);
        }
        #pragma unroll
        for (int nf = 0; nf < 4; ++nf) {
            const size_t bo = (size_t)(n0 + nf * 16 + lrow) * DM + k0;
            f16x8 bh_ = *(const f16x8*)&Bhi[bo];
            f16x8 bl_ = *(const f16x8*)&Blo[bo];
            acc[nf] = MFMA_F16(ah, bh_, acc[nf]);
            acc[nf] = MFMA_F16(al, bh_, acc[nf]);
            acc[nf] = MFMA_F16(ah, bl_, acc[nf]);
        }
    }

    float bb[4];
    #pragma unroll
    for (int nf = 0; nf < 4; ++nf) bb[nf] = bias[n0 + nf * 16 + lrow];

    if (MODE == 0) {
        const int h = blockIdx.x;  // N-tile == head since DK == 64
        #pragma unroll
        for (int nf = 0; nf < 4; ++nf)
            #pragma unroll
            for (int r = 0; r < 4; ++r) {
                int m = m0 + wave * 16 + grow + r;
                int b_ = m >> 11, s_ = m & 2047;
                float v = acc[nf][r] + bb[nf];
                _Float16 h16 = (_Float16)v;
                size_t o = (((size_t)(b_ * HH + h) * SS + s_) << 6) + nf * 16 + lrow;
                Chi[o] = h16;
                Clo[o] = (_Float16)(v - (float)h16);
            }
    } else if (MODE == 1) {
        __shared__ _Float16 T[2][64][72];
        #pragma unroll
        for (int nf = 0; nf < 4; ++nf)
            #pragma unroll
            for (int r = 0; r < 4; ++r) {
                float v = acc[nf][r] + bb[nf];
                _Float16 h16 = (_Float16)v;
                int ml = wave * 16 + grow + r;
                T[0][nf * 16 + lrow][ml] = h16;
                T[1][nf * 16 + lrow][ml] = (_Float16)(v - (float)h16);
            }
        __syncthreads();
        const int h  = blockIdx.x;
        const int b_ = m0 >> 11, s0 = m0 & 2047;
        int row = tid >> 1;
        int p = row >> 6, dk = row & 63, sh = (tid & 1) * 32;
        const _Float16* src = &T[p][dk][sh];
        _Float16* dst = (p ? Clo : Chi) +
                        ((size_t)(b_ * HH + h) * DK + dk) * SS + s0 + sh;
        #pragma unroll
        for (int j = 0; j < 32; j += 8)
            *(f16x8*)&dst[j] = *(const f16x8*)&src[j];
    } else {
        #pragma unroll
        for (int nf = 0; nf < 4; ++nf)
            #pragma unroll
            for (int r = 0; r < 4; ++r) {
                int m = m0 + wave * 16 + grow + r;
                Cf[(size_t)m * DM + n0 + nf * 16 + lrow] = acc[nf][r] + bb[nf];
            }
    }
}

// ---------------------------------------------------------------------------
// Fused attention, single pass, split-fp16 MFMA, self-normalizing.
// Per wave (16 q rows): stream all 2048 keys once. s via two independent
// 3-MFMA chains; p' = exp(s/8) UNNORMALIZED -> attnW; row-sum accumulated
// inline; P' (x16: clear of f16 denorm floor, overflow-safe to z~8.3)
// transposed C->A layout via per-wave LDS; O += P'@V. Epilogue: rl = 1/l,
// in-place float4 RMW normalize of this wave's own 16 attnW rows (L2-hot),
// ctx written scaled by rl/16. No extra workspace, no extra kernel.
// ---------------------------------------------------------------------------
__global__ __launch_bounds__(256) void attn_kernel(
        const _Float16* __restrict__ Qhi, const _Float16* __restrict__ Qlo,
        const _Float16* __restrict__ Khi, const _Float16* __restrict__ Klo,
        const _Float16* __restrict__ Vthi, const _Float16* __restrict__ Vtlo,
        float* __restrict__ attnW, float* __restrict__ ctx)
{
    __shared__ float Ps[4][16][34];   // per-wave P-transpose tile (+2 pad; col 32 = rl)

    const int tid  = threadIdx.x;
    const int wave = tid >> 6;
    const int lane = tid & 63;
    const int lrow = lane & 15;
    const int lk   = (lane >> 4) * 8;
    const int grow = (lane >> 4) * 4;

    const int qt = blockIdx.x;         // 0..31
    const int bh = blockIdx.y;         // 0..23
    const int qw0 = qt * 64 + wave * 16;
    const size_t qkbase = (size_t)bh * SS * DK;  // halves, [bh][s][dk]
    const size_t vbase  = (size_t)bh * DK * SS;  // halves, [bh][dk][s]

    f16x8 qhi[2], qlo[2];
    {
        const size_t qidx = qkbase + (size_t)(qw0 + lrow) * DK + lk;
        qhi[0] = *(const f16x8*)&Qhi[qidx];
        qhi[1] = *(const f16x8*)&Qhi[qidx + 32];
        qlo[0] = *(const f16x8*)&Qlo[qidx];
        qlo[1] = *(const f16x8*)&Qlo[qidx + 32];
    }

    float lsum[4] = {0.f, 0.f, 0.f, 0.f};
    f32x4 Oacc[4];
    #pragma unroll
    for (int n = 0; n < 4; ++n) Oacc[n] = (f32x4){0.f, 0.f, 0.f, 0.f};

    float (*ps)[34] = Ps[wave];

    for (int kt = 0; kt < 64; ++kt) {           // 32 keys per iteration
        #pragma unroll
        for (int sub = 0; sub < 2; ++sub) {
            const int k16 = kt * 2 + sub;
            const size_t kidx = qkbase + (size_t)(k16 * 16 + lrow) * DK + lk;
            f16x8 khi0 = *(const f16x8*)&Khi[kidx];
            f16x8 khi1 = *(const f16x8*)&Khi[kidx + 32];
            f16x8 klo0 = *(const f16x8*)&Klo[kidx];
            f16x8 klo1 = *(const f16x8*)&Klo[kidx + 32];
            // two independent 3-MFMA chains for ILP
            f32x4 cA = {0.f, 0.f, 0.f, 0.f};
            f32x4 cB = {0.f, 0.f, 0.f, 0.f};
            cA = MFMA_F16(qhi[0], khi0, cA);
            cA = MFMA_F16(qhi[1], khi1, cA);
            cA = MFMA_F16(qlo[0], khi0, cA);
            cB = MFMA_F16(qlo[1], khi1, cB);
            cB = MFMA_F16(qhi[0], klo0, cB);
            cB = MFMA_F16(qhi[1], klo1, cB);
            #pragma unroll
            for (int r = 0; r < 4; ++r) {
                float pv = __expf((cA[r] + cB[r]) * 0.125f);   // unnormalized
                lsum[r] += pv;
                attnW[((size_t)bh * SS + qw0 + grow + r) * SS + k16 * 16 + lrow] = pv;
                ps[grow + r][sub * 16 + lrow] = pv * 16.0f;
            }
        }
        // wave-synchronous LDS transpose: C-layout -> A-layout
        float pf[8];
        #pragma unroll
        for (int j = 0; j < 8; ++j) pf[j] = ps[lrow][lk + j];
        f16x8 phi, plo;
        #pragma unroll
        for (int j = 0; j < 8; ++j) {
            _Float16 h = (_Float16)pf[j];
            phi[j] = h;
            plo[j] = (_Float16)(pf[j] - (float)h);
        }
        #pragma unroll
        for (int n = 0; n < 4; ++n) {
            const size_t vidx = vbase + (size_t)(n * 16 + lrow) * SS + kt * 32 + lk;
            f16x8 vhi = *(const f16x8*)&Vthi[vidx];
            f16x8 vlo = *(const f16x8*)&Vtlo[vidx];
            Oacc[n] = MFMA_F16(phi, vhi, Oacc[n]);
            Oacc[n] = MFMA_F16(plo, vhi, Oacc[n]);
            Oacc[n] = MFMA_F16(phi, vlo, Oacc[n]);
        }
    }

    // reduce row sums across the 16 lanes sharing each row group
    #pragma unroll
    for (int r = 0; r < 4; ++r) {
        lsum[r] += __shfl_xor(lsum[r], 1, 64);
        lsum[r] += __shfl_xor(lsum[r], 2, 64);
        lsum[r] += __shfl_xor(lsum[r], 4, 64);
        lsum[r] += __shfl_xor(lsum[r], 8, 64);
    }
    float rl[4];
    #pragma unroll
    for (int r = 0; r < 4; ++r) rl[r] = 1.0f / lsum[r];

    // stage rl for all 16 rows into LDS pad column (wave-synchronous)
    if (lrow == 0) {
        #pragma unroll
        for (int r = 0; r < 4; ++r) ps[grow + r][32] = rl[r];
    }

    // in-place normalize this wave's own 16 attnW rows (coalesced, L2-hot)
    for (int r16 = 0; r16 < 16; ++r16) {
        float mrl = ps[r16][32];
        float4* row4 = (float4*)&attnW[((size_t)bh * SS + qw0 + r16) * SS];
        #pragma unroll
        for (int it = 0; it < 8; ++it) {
            float4 vv = row4[it * 64 + lane];
            vv.x *= mrl; vv.y *= mrl; vv.z *= mrl; vv.w *= mrl;
            row4[it * 64 + lane] = vv;
        }
    }

    // ctx fp32 [B,S,768]; undo the x16 P scaling and normalize
    const int b_ = bh / HH, h_ = bh % HH;
    #pragma unroll
    for (int n = 0; n < 4; ++n)
        #pragma unroll
        for (int r = 0; r < 4; ++r) {
            int q = qw0 + grow + r;
            ctx[((size_t)b_ * SS + q) * DM + h_ * DK + n * 16 + lrow] =
                Oacc[n][r] * rl[r] * 0.0625f;
        }
}

// ---------------------------------------------------------------------------
// final copy: out <- res (fp32, 12.6 MB), pure BW-bound
// ---------------------------------------------------------------------------
__global__ __launch_bounds__(256) void copy_kernel(
        float* __restrict__ dst, const float* __restrict__ src)
{
    const size_t total4 = (size_t)2 * SS * DM / 4;   // 786,432 float4
    size_t i = (size_t)blockIdx.x * 256 + threadIdx.x;
    const size_t stride = (size_t)gridDim.x * 256;
    float4* d4 = (float4*)dst;
    const float4* s4 = (const float4*)src;
    for (; i < total4; i += stride) d4[i] = s4[i];
}

extern "C" void kernel_launch(void* const* d_in, const int* in_sizes, int n_in,
                              void* d_out, int out_size, void* d_ws, size_t ws_size,
                              hipStream_t stream) {
    const float* q   = (const float*)d_in[0];
    const float* k   = (const float*)d_in[1];
    const float* v   = (const float*)d_in[2];
    const float* w_q = (const float*)d_in[3];
    const float* b_q = (const float*)d_in[4];
    const float* w_k = (const float*)d_in[5];
    const float* b_k = (const float*)d_in[6];
    const float* w_v = (const float*)d_in[7];
    const float* b_v = (const float*)d_in[8];
    const float* w_o = (const float*)d_in[9];
    const float* b_o = (const float*)d_in[10];

    float* out   = (float*)d_out;                    // [2,2048,768]
    float* attnW = out + (size_t)2 * SS * DM;        // [2,12,2048,2048]

    // ---- workspace: EXACTLY the 50,331,648-byte footprint that passed ----
    _Float16* wsh = (_Float16*)d_ws;
    const size_t PL = (size_t)2 * HH * SS * DK;      // 3,145,728 halves / plane
    _Float16* Qhi  = wsh;
    _Float16* Qlo  = wsh + PL;
    _Float16* Khi  = wsh + 2 * PL;
    _Float16* Klo  = wsh + 3 * PL;
    _Float16* Vthi = wsh + 4 * PL;
    _Float16* Vtlo = wsh + 5 * PL;
    float* ctx = (float*)(wsh + 6 * PL);             // [2,2048,768] fp32
    float* res = (float*)wsh;                        // final-out scratch over dead Q planes

    // ---- pre-attn weight scratch parked inside the attnW output region ----
    const size_t WPL = (size_t)DM * DM;              // 589,824 halves / plane
    _Float16* WtQ_hi = (_Float16*)attnW;
    _Float16* WtQ_lo = WtQ_hi + WPL;
    _Float16* WtK_hi = WtQ_hi + 2 * WPL;
    _Float16* WtK_lo = WtQ_hi + 3 * WPL;
    _Float16* WtV_hi = WtQ_hi + 4 * WPL;
    _Float16* WtV_lo = WtQ_hi + 5 * WPL;
    // ---- W_o scratch parked inside the `out` region (consumed before copy) ----
    _Float16* WtO_hi = (_Float16*)out;
    _Float16* WtO_lo = WtO_hi + WPL;

    dim3 blk(256);
    conv_w_kernel<<<dim3(12, 12, 4), blk, 0, stream>>>(
        w_q, w_k, w_v, w_o,
        WtQ_hi, WtQ_lo, WtK_hi, WtK_lo, WtV_hi, WtV_lo, WtO_hi, WtO_lo);

    dim3 gg(12, 64);
    gemm16_kernel<0><<<gg, blk, 0, stream>>>(q, WtQ_hi, WtQ_lo, b_q, Qhi, Qlo, nullptr);
    gemm16_kernel<0><<<gg, blk, 0, stream>>>(k, WtK_hi, WtK_lo, b_k, Khi, Klo, nullptr);
    gemm16_kernel<1><<<gg, blk, 0, stream>>>(v, WtV_hi, WtV_lo, b_v, Vthi, Vtlo, nullptr);

    attn_kernel<<<dim3(32, 24), blk, 0, stream>>>(Qhi, Qlo, Khi, Klo, Vthi, Vtlo,
                                                  attnW, ctx);

    gemm16_kernel<2><<<gg, blk, 0, stream>>>(ctx, WtO_hi, WtO_lo, b_o,
                                             nullptr, nullptr, res);

    copy_kernel<<<dim3(1024), blk, 0, stream>>>(out, res);
}